// Round 5
// baseline (185.639 us; speedup 1.0000x reference)
//
#include <hip/hip_runtime.h>

#define EPSILON 0.05f
#define NSLOTS 64

typedef float v4f __attribute__((ext_vector_type(4)));

// Phase 1: dual binary search per ray (one lane = one ray).
// z rows are sorted, so lower = #{z < d-eps}, upper = #{z < d+eps} are
// lower_bound positions. 10 fixed iterations (span 1024 -> 1), two
// independent probe loads per step. Packs lower | upper<<16 (both <= 1024).
__global__ __launch_bounds__(64) void sight_search_1024(
    const float* __restrict__ ray_depth,
    const float* __restrict__ z_vals,
    int* __restrict__ lu,
    int n_rays)
{
    const int r = blockIdx.x * 64 + threadIdx.x;
    const bool valid = (r < n_rays);
    const int rc = valid ? r : 0;

    const float d  = ray_depth[rc];
    const float lo = d - EPSILON;
    const float hi = d + EPSILON;
    const float* zr = z_vals + (size_t)rc * 1024;

    int l1 = 0, r1 = 1024, l2 = 0, r2 = 1024;
    #pragma unroll
    for (int it = 0; it < 10; ++it) {
        const int m1 = (l1 + r1) >> 1;
        const int m2 = (l2 + r2) >> 1;
        const float a = zr[m1];
        const float b = zr[m2];
        if (a < lo) l1 = m1 + 1; else r1 = m1;
        if (b < hi) l2 = m2 + 1; else r2 = m2;
    }
    if (valid) lu[r] = l1 | (l2 << 16);
}

// Phase 2: one wave per ray, reads ONLY w[0..upper) (ceil(upper/256) chunks
// of 1 KiB; avg ~2.75 of 4). Terms match the full elementwise kernel exactly:
// j < lower  <=>  z[j] < lo,  lower <= j < upper  <=>  lo <= z[j] < hi.
__global__ __launch_bounds__(256, 8) void sight_near_loss_1024(
    const float* __restrict__ weights,     // [N, 1024]
    const int*   __restrict__ lu,          // [N] packed lower|upper<<16
    const int*   __restrict__ ray_mask,    // [N]
    float* __restrict__ partials,          // [3*NSLOTS]
    int n_rays)
{
    const int lane = threadIdx.x & 63;
    const int r = __builtin_amdgcn_readfirstlane(blockIdx.x * 4 + (threadIdx.x >> 6));
    if (r >= n_rays) return;

    const int pk    = lu[r];               // wave-uniform scalar load
    const int msk   = ray_mask[r];
    const int lower = pk & 0xffff;
    const int upper = pk >> 16;
    const int steps = (upper + 255) >> 8;  // chunks of 256 floats

    const v4f* w4 = (const v4f*)(weights + (size_t)r * 1024);

    v4f wv[4];
    #pragma unroll
    for (int s = 0; s < 4; ++s) {
        if (s < steps) wv[s] = w4[lane + 64 * s];   // wave-uniform guard
        else           wv[s] = (v4f){0.0f, 0.0f, 0.0f, 0.0f};
    }

    float empty = 0.0f, wnear = 0.0f;
    #pragma unroll
    for (int s = 0; s < 4; ++s) {
        const int j0 = 4 * (lane + 64 * s);
        #pragma unroll
        for (int c = 0; c < 4; ++c) {
            const int   j = j0 + c;
            const float w = wv[s][c];
            empty += (j < lower) ? w * w : 0.0f;
            wnear += (j >= lower && j < upper) ? w : 0.0f;
        }
    }

    #pragma unroll
    for (int off = 32; off > 0; off >>= 1) {
        empty += __shfl_xor(empty, off, 64);
        wnear += __shfl_xor(wnear, off, 64);
    }

    if (lane == 0 && msk != 0) {
        const int slot = r & (NSLOTS - 1);
        const float t = 1.0f - wnear;
        atomicAdd(&partials[slot],              empty);
        atomicAdd(&partials[NSLOTS + slot],     t * t);
        atomicAdd(&partials[2 * NSLOTS + slot], 1.0f);
    }
}

// Generic fallback (runtime S): full elementwise pass.
__global__ __launch_bounds__(256) void sight_near_loss_generic(
    const float* __restrict__ ray_depth,
    const float* __restrict__ z_vals,
    const float* __restrict__ weights,
    const int*   __restrict__ ray_mask,
    float* __restrict__ partials,
    int n_rays, int S)
{
    const int wave = threadIdx.x >> 6;
    const int lane = threadIdx.x & 63;
    const int r = blockIdx.x * 4 + wave;
    if (r >= n_rays) return;

    const float d  = ray_depth[r];
    const float lo = d - EPSILON;
    const float hi = d + EPSILON;

    float empty = 0.0f, wnear = 0.0f;
    const float* zr = z_vals  + (size_t)r * S;
    const float* wr = weights + (size_t)r * S;
    for (int k = lane; k < S; k += 64) {
        const float z = zr[k];
        const float w = wr[k];
        empty += (z < lo) ? w * w : 0.0f;
        wnear += (z >= lo && z < hi) ? w : 0.0f;
    }
    #pragma unroll
    for (int off = 32; off > 0; off >>= 1) {
        empty += __shfl_xor(empty, off, 64);
        wnear += __shfl_xor(wnear, off, 64);
    }
    if (lane == 0 && ray_mask[r] != 0) {
        const int slot = r & (NSLOTS - 1);
        const float t = 1.0f - wnear;
        atomicAdd(&partials[slot],              empty);
        atomicAdd(&partials[NSLOTS + slot],     t * t);
        atomicAdd(&partials[2 * NSLOTS + slot], 1.0f);
    }
}

__global__ void sight_near_finalize_kernel(
    const float* __restrict__ partials, float* __restrict__ out)
{
    const int lane = threadIdx.x;  // 64 threads
    float e = partials[lane];
    float n = partials[NSLOTS + lane];
    float m = partials[2 * NSLOTS + lane];
    #pragma unroll
    for (int off = 32; off > 0; off >>= 1) {
        e += __shfl_xor(e, off, 64);
        n += __shfl_xor(n, off, 64);
        m += __shfl_xor(m, off, 64);
    }
    if (lane == 0) {
        out[0] = e / m;   // loss_empty
        out[1] = n / m;   // loss_near
    }
}

extern "C" void kernel_launch(void* const* d_in, const int* in_sizes, int n_in,
                              void* d_out, int out_size, void* d_ws, size_t ws_size,
                              hipStream_t stream) {
    const float* ray_depth = (const float*)d_in[0];
    const float* z_vals    = (const float*)d_in[1];
    const float* weights   = (const float*)d_in[2];
    const int*   ray_mask  = (const int*)d_in[3];

    const int n_rays = in_sizes[0];                // ray_depth is [N,1]
    const int S      = in_sizes[1] / n_rays;       // 1024

    float* partials = (float*)d_ws;                          // 192 floats
    int*   lu       = (int*)((char*)d_ws + 1024);            // N packed ints
    hipMemsetAsync(partials, 0, 3 * NSLOTS * sizeof(float), stream);

    if (S == 1024) {
        const int sblocks = (n_rays + 63) / 64;
        sight_search_1024<<<sblocks, 64, 0, stream>>>(
            ray_depth, z_vals, lu, n_rays);
        const int blocks = (n_rays + 3) / 4;       // 4 waves (rays) per block
        sight_near_loss_1024<<<blocks, 256, 0, stream>>>(
            weights, lu, ray_mask, partials, n_rays);
    } else {
        const int blocks = (n_rays + 3) / 4;
        sight_near_loss_generic<<<blocks, 256, 0, stream>>>(
            ray_depth, z_vals, weights, ray_mask, partials, n_rays, S);
    }
    sight_near_finalize_kernel<<<1, 64, 0, stream>>>(partials, (float*)d_out);
}

// Round 6
// 152.234 us; speedup vs baseline: 1.2194x; 1.2194x over previous
//
#include <hip/hip_runtime.h>

#define EPSILON 0.05f
#define NSLOTS 64

typedef float v4f __attribute__((ext_vector_type(4)));

// Phase 1: dual binary search per ray (1 thread/ray). Packs
// lower | upper<<16 | mask<<31 so the streaming kernel needs only lu+weights.
__global__ __launch_bounds__(256) void sight_search_1024(
    const float* __restrict__ ray_depth,
    const float* __restrict__ z_vals,
    const int*   __restrict__ ray_mask,
    int* __restrict__ lu,
    int n_rays)
{
    const int r = blockIdx.x * 256 + threadIdx.x;
    const bool valid = (r < n_rays);
    const int rc = valid ? r : 0;

    const float d  = ray_depth[rc];
    const float lo = d - EPSILON;
    const float hi = d + EPSILON;
    const float* zr = z_vals + (size_t)rc * 1024;

    int l1 = 0, r1 = 1024, l2 = 0, r2 = 1024;
    #pragma unroll
    for (int it = 0; it < 10; ++it) {
        const int m1 = (l1 + r1) >> 1;
        const int m2 = (l2 + r2) >> 1;
        const float a = zr[m1];
        const float b = zr[m2];
        if (a < lo) l1 = m1 + 1; else r1 = m1;
        if (b < hi) l2 = m2 + 1; else r2 = m2;
    }
    const unsigned pk = (unsigned)l1 | ((unsigned)l2 << 16)
                      | (ray_mask[rc] != 0 ? 0x80000000u : 0u);
    if (valid) lu[r] = (int)pk;
}

// Phase 2: PERSISTENT waves. 2048 waves, each loops over rays with stride
// nwaves (8 rays/wave at N=16384). Per iteration one asm block issues the
// ray's 4 w-chunks AND its lu word concurrently (lu no longer serializes
// ahead of the vector loads), one vmcnt(0) drain per ray. Long-lived waves
// fix the R0-R5 invariant: short per-ray waves capped effective memory
// concurrency at ~1 wave/CU (~2.3 TB/s wall) regardless of grid shape.
__global__ __launch_bounds__(256, 8) void sight_stream_1024(
    const float* __restrict__ weights,     // [N, 1024]
    const int*   __restrict__ lu,          // [N] lower|upper<<16|mask<<31
    float* __restrict__ partials,          // [3*NSLOTS]
    int n_rays, int nwaves)
{
    const int lane = threadIdx.x & 63;
    const int wave = __builtin_amdgcn_readfirstlane(
        (int)((blockIdx.x * blockDim.x + threadIdx.x) >> 6));
    const int voff = lane * 16;

    float e_lane = 0.0f;   // per-lane sum fm * w^2 * [j < lower]
    float n_acc  = 0.0f;   // fm * (1 - w_near)^2   (lane-uniform)
    float m_acc  = 0.0f;   // fm count              (lane-uniform)

    for (int r = wave; r < n_rays; r += nwaves) {
        const float* wb  = weights + (size_t)r * 1024;
        const int*   lup = lu + r;

        v4f w0, w1, w2, w3;
        int pk;
        asm volatile(
            "global_load_dwordx4 %0, %5, %6 offset:0\n\t"
            "global_load_dwordx4 %1, %5, %6 offset:1024\n\t"
            "global_load_dwordx4 %2, %5, %6 offset:2048\n\t"
            "global_load_dwordx4 %3, %5, %6 offset:3072\n\t"
            "global_load_dword   %4, %7, %8\n\t"
            "s_waitcnt vmcnt(0)"
            : "=v"(w0), "=v"(w1), "=v"(w2), "=v"(w3), "=v"(pk)
            : "v"(voff), "s"(wb), "v"(0), "s"(lup)
            : "memory");

        const unsigned pku = (unsigned)pk;
        const int   lower = (int)(pku & 0xffffu);
        const int   upper = (int)((pku >> 16) & 0x7fffu);
        const float fm    = (pku >> 31) ? 1.0f : 0.0f;

        float emp = 0.0f, wnr = 0.0f;
        v4f wv[4] = {w0, w1, w2, w3};
        #pragma unroll
        for (int p = 0; p < 4; ++p) {
            const int j0 = 256 * p + 4 * lane;
            #pragma unroll
            for (int c = 0; c < 4; ++c) {
                const int   j = j0 + c;
                const float w = wv[p][c];
                emp += (j < lower) ? w * w : 0.0f;
                wnr += (j >= lower && j < upper) ? w : 0.0f;
            }
        }

        #pragma unroll
        for (int off = 32; off > 0; off >>= 1) wnr += __shfl_xor(wnr, off, 64);

        const float t = 1.0f - wnr;
        e_lane += fm * emp;
        n_acc  += fm * t * t;
        m_acc  += fm;
    }

    #pragma unroll
    for (int off = 32; off > 0; off >>= 1) e_lane += __shfl_xor(e_lane, off, 64);

    if (lane == 0) {
        const int slot = wave & (NSLOTS - 1);
        atomicAdd(&partials[slot],              e_lane);
        atomicAdd(&partials[NSLOTS + slot],     n_acc);
        atomicAdd(&partials[2 * NSLOTS + slot], m_acc);
    }
}

// Generic fallback (runtime S): full elementwise pass.
__global__ __launch_bounds__(256) void sight_near_loss_generic(
    const float* __restrict__ ray_depth,
    const float* __restrict__ z_vals,
    const float* __restrict__ weights,
    const int*   __restrict__ ray_mask,
    float* __restrict__ partials,
    int n_rays, int S)
{
    const int wave = threadIdx.x >> 6;
    const int lane = threadIdx.x & 63;
    const int r = blockIdx.x * 4 + wave;
    if (r >= n_rays) return;

    const float d  = ray_depth[r];
    const float lo = d - EPSILON;
    const float hi = d + EPSILON;

    float empty = 0.0f, wnear = 0.0f;
    const float* zr = z_vals  + (size_t)r * S;
    const float* wr = weights + (size_t)r * S;
    for (int k = lane; k < S; k += 64) {
        const float z = zr[k];
        const float w = wr[k];
        empty += (z < lo) ? w * w : 0.0f;
        wnear += (z >= lo && z < hi) ? w : 0.0f;
    }
    #pragma unroll
    for (int off = 32; off > 0; off >>= 1) {
        empty += __shfl_xor(empty, off, 64);
        wnear += __shfl_xor(wnear, off, 64);
    }
    if (lane == 0 && ray_mask[r] != 0) {
        const int slot = r & (NSLOTS - 1);
        const float t = 1.0f - wnear;
        atomicAdd(&partials[slot],              empty);
        atomicAdd(&partials[NSLOTS + slot],     t * t);
        atomicAdd(&partials[2 * NSLOTS + slot], 1.0f);
    }
}

__global__ void sight_near_finalize_kernel(
    const float* __restrict__ partials, float* __restrict__ out)
{
    const int lane = threadIdx.x;  // 64 threads
    float e = partials[lane];
    float n = partials[NSLOTS + lane];
    float m = partials[2 * NSLOTS + lane];
    #pragma unroll
    for (int off = 32; off > 0; off >>= 1) {
        e += __shfl_xor(e, off, 64);
        n += __shfl_xor(n, off, 64);
        m += __shfl_xor(m, off, 64);
    }
    if (lane == 0) {
        out[0] = e / m;   // loss_empty
        out[1] = n / m;   // loss_near
    }
}

extern "C" void kernel_launch(void* const* d_in, const int* in_sizes, int n_in,
                              void* d_out, int out_size, void* d_ws, size_t ws_size,
                              hipStream_t stream) {
    const float* ray_depth = (const float*)d_in[0];
    const float* z_vals    = (const float*)d_in[1];
    const float* weights   = (const float*)d_in[2];
    const int*   ray_mask  = (const int*)d_in[3];

    const int n_rays = in_sizes[0];                // ray_depth is [N,1]
    const int S      = in_sizes[1] / n_rays;       // 1024

    float* partials = (float*)d_ws;                          // 192 floats
    int*   lu       = (int*)((char*)d_ws + 1024);            // N packed ints
    hipMemsetAsync(partials, 0, 3 * NSLOTS * sizeof(float), stream);

    if (S == 1024) {
        const int sblocks = (n_rays + 255) / 256;
        sight_search_1024<<<sblocks, 256, 0, stream>>>(
            ray_depth, z_vals, ray_mask, lu, n_rays);

        const int blocks = 512;                    // persistent: 2048 waves
        const int nwaves = blocks * 4;
        sight_stream_1024<<<blocks, 256, 0, stream>>>(
            weights, lu, partials, n_rays, nwaves);
    } else {
        const int blocks = (n_rays + 3) / 4;
        sight_near_loss_generic<<<blocks, 256, 0, stream>>>(
            ray_depth, z_vals, weights, ray_mask, partials, n_rays, S);
    }
    sight_near_finalize_kernel<<<1, 64, 0, stream>>>(partials, (float*)d_out);
}

// Round 7
// 142.563 us; speedup vs baseline: 1.3022x; 1.0678x over previous
//
#include <hip/hip_runtime.h>

#define EPSILON 0.05f
#define NW 2048   // persistent waves in fused kernel (512 blocks x 4 waves)

typedef float v4f __attribute__((ext_vector_type(4)));

// Fused persistent kernel (S=1024). Phase A (prologue): lane j dual-binary-
// searches ray (wave + j*NW): lower=#{z<d-eps}, upper=#{z<d+eps}, packed with
// mask into a register. Phase B: loop over the wave's rays in PAIRS; bounds
// come from v_readlane (registers -- no lu memory round-trip, R5's flaw), so
// only ceil(upper/256) w-chunks are issued per ray (avg ~2.75/4 => ~45 MB
// instead of 64 MB). ~5.5 KB in flight per wave per drain. Direct-write
// per-wave partial slots: no atomics, no zero-init needed.
__global__ __launch_bounds__(256, 4) void sight_fused_1024(
    const float* __restrict__ ray_depth,   // [N]
    const float* __restrict__ z_vals,      // [N, 1024] sorted rows
    const float* __restrict__ weights,     // [N, 1024]
    const int*   __restrict__ ray_mask,    // [N]
    float* __restrict__ partials,          // [3*NW]
    int n_rays)
{
    const int lane = threadIdx.x & 63;
    const int wave = (int)((blockIdx.x * blockDim.x + threadIdx.x) >> 6); // 0..NW-1
    const int rpw  = (n_rays + NW - 1) / NW;   // rays per wave (<=64)

    // ---- Phase A: per-lane dual binary search ----
    const int  rj = wave + lane * NW;
    const bool vld = (lane < rpw) && (rj < n_rays);
    const int  rc = vld ? rj : 0;
    const float d  = ray_depth[rc];
    const float lo = d - EPSILON;
    const float hi = d + EPSILON;
    const float* zr = z_vals + (size_t)rc * 1024;
    int l1 = 0, h1 = 1024, l2 = 0, h2 = 1024;
    #pragma unroll
    for (int it = 0; it < 10; ++it) {
        const int m1 = (l1 + h1) >> 1;
        const int m2 = (l2 + h2) >> 1;
        const float a = zr[m1];
        const float b = zr[m2];
        if (a < lo) l1 = m1 + 1; else h1 = m1;
        if (b < hi) l2 = m2 + 1; else h2 = m2;
    }
    const int mk = ray_mask[rc];
    const int mypk = vld
        ? (int)((unsigned)l1 | ((unsigned)l2 << 16) | (mk != 0 ? 0x80000000u : 0u))
        : 0;

    // ---- Phase B: stream weights, ray pairs ----
    float e_lane = 0.0f;   // sum fm * w^2 over [0, lower)
    float n_acc  = 0.0f;   // sum fm * (1 - w_near)^2
    float m_acc  = 0.0f;   // sum fm

    for (int i = 0; i < rpw; i += 2) {
        const int pkA = __builtin_amdgcn_readlane(mypk, i);
        const int pkB = (i + 1 < rpw) ? __builtin_amdgcn_readlane(mypk, i + 1) : 0;

        const int   lowA = pkA & 0xffff,          lowB = pkB & 0xffff;
        const int   upA  = (pkA >> 16) & 0x7fff,  upB  = (pkB >> 16) & 0x7fff;
        const float fmA  = ((unsigned)pkA >> 31) ? 1.0f : 0.0f;
        const float fmB  = ((unsigned)pkB >> 31) ? 1.0f : 0.0f;
        const int   stA  = (upA + 255) >> 8;      // chunks needed (0..4)
        const int   stB  = (upB + 255) >> 8;

        const v4f* wA = (const v4f*)(weights + (size_t)wave * 1024 + (size_t)i * NW * 1024);
        const v4f* wB = (const v4f*)(weights + (size_t)wave * 1024 + (size_t)(i + 1) * NW * 1024);

        v4f a[4], b[4];
        #pragma unroll
        for (int s = 0; s < 4; ++s)
            a[s] = (s < stA) ? wA[lane + 64 * s] : (v4f){0.0f, 0.0f, 0.0f, 0.0f};
        #pragma unroll
        for (int s = 0; s < 4; ++s)
            b[s] = (s < stB) ? wB[lane + 64 * s] : (v4f){0.0f, 0.0f, 0.0f, 0.0f};

        float eA = 0.0f, wnA = 0.0f, eB = 0.0f, wnB = 0.0f;
        #pragma unroll
        for (int s = 0; s < 4; ++s) {
            #pragma unroll
            for (int c = 0; c < 4; ++c) {
                const int   j  = 256 * s + 4 * lane + c;
                const float wa = a[s][c];
                const float wb = b[s][c];
                eA  += (j < lowA) ? wa * wa : 0.0f;
                wnA += (j >= lowA && j < upA) ? wa : 0.0f;
                eB  += (j < lowB) ? wb * wb : 0.0f;
                wnB += (j >= lowB && j < upB) ? wb : 0.0f;
            }
        }
        #pragma unroll
        for (int off = 32; off > 0; off >>= 1) {
            wnA += __shfl_xor(wnA, off, 64);
            wnB += __shfl_xor(wnB, off, 64);
        }
        const float tA = 1.0f - wnA, tB = 1.0f - wnB;
        e_lane += fmA * eA + fmB * eB;
        n_acc  += fmA * tA * tA + fmB * tB * tB;
        m_acc  += fmA + fmB;
    }

    #pragma unroll
    for (int off = 32; off > 0; off >>= 1) e_lane += __shfl_xor(e_lane, off, 64);

    if (lane == 0) {
        partials[wave]          = e_lane;
        partials[NW + wave]     = n_acc;
        partials[2 * NW + wave] = m_acc;
    }
}

// Generic fallback (runtime S): full elementwise pass, atomics into the
// same [3*NW] partials (requires the memset the launcher issues on this path).
__global__ __launch_bounds__(256) void sight_near_loss_generic(
    const float* __restrict__ ray_depth,
    const float* __restrict__ z_vals,
    const float* __restrict__ weights,
    const int*   __restrict__ ray_mask,
    float* __restrict__ partials,
    int n_rays, int S)
{
    const int wv = threadIdx.x >> 6;
    const int lane = threadIdx.x & 63;
    const int r = blockIdx.x * 4 + wv;
    if (r >= n_rays) return;

    const float d  = ray_depth[r];
    const float lo = d - EPSILON;
    const float hi = d + EPSILON;

    float empty = 0.0f, wnear = 0.0f;
    const float* zr = z_vals  + (size_t)r * S;
    const float* wr = weights + (size_t)r * S;
    for (int k = lane; k < S; k += 64) {
        const float z = zr[k];
        const float w = wr[k];
        empty += (z < lo) ? w * w : 0.0f;
        wnear += (z >= lo && z < hi) ? w : 0.0f;
    }
    #pragma unroll
    for (int off = 32; off > 0; off >>= 1) {
        empty += __shfl_xor(empty, off, 64);
        wnear += __shfl_xor(wnear, off, 64);
    }
    if (lane == 0 && ray_mask[r] != 0) {
        const int slot = r & (NW - 1);
        const float t = 1.0f - wnear;
        atomicAdd(&partials[slot],          empty);
        atomicAdd(&partials[NW + slot],     t * t);
        atomicAdd(&partials[2 * NW + slot], 1.0f);
    }
}

// Reduce [3*NW] partials with one wave (v4f loads: 8 x 1KB per stream).
__global__ void sight_finalize(const float* __restrict__ partials,
                               float* __restrict__ out)
{
    const int lane = threadIdx.x;  // 64 threads
    const v4f* p = (const v4f*)partials;   // each array = NW/4 = 512 v4f
    v4f e4 = {0,0,0,0}, n4 = {0,0,0,0}, m4 = {0,0,0,0};
    #pragma unroll
    for (int k = 0; k < NW / 4 / 64; ++k) {   // 8
        e4 += p[lane + 64 * k];
        n4 += p[512 + lane + 64 * k];
        m4 += p[1024 + lane + 64 * k];
    }
    float e = e4.x + e4.y + e4.z + e4.w;
    float n = n4.x + n4.y + n4.z + n4.w;
    float m = m4.x + m4.y + m4.z + m4.w;
    #pragma unroll
    for (int off = 32; off > 0; off >>= 1) {
        e += __shfl_xor(e, off, 64);
        n += __shfl_xor(n, off, 64);
        m += __shfl_xor(m, off, 64);
    }
    if (lane == 0) {
        out[0] = e / m;   // loss_empty
        out[1] = n / m;   // loss_near
    }
}

extern "C" void kernel_launch(void* const* d_in, const int* in_sizes, int n_in,
                              void* d_out, int out_size, void* d_ws, size_t ws_size,
                              hipStream_t stream) {
    const float* ray_depth = (const float*)d_in[0];
    const float* z_vals    = (const float*)d_in[1];
    const float* weights   = (const float*)d_in[2];
    const int*   ray_mask  = (const int*)d_in[3];

    const int n_rays = in_sizes[0];                // ray_depth is [N,1]
    const int S      = in_sizes[1] / n_rays;       // 1024

    float* partials = (float*)d_ws;                // 3*NW floats = 24 KB

    if (S == 1024 && n_rays <= NW * 64) {
        // fused path writes every slot directly -- no memset needed
        sight_fused_1024<<<NW / 4, 256, 0, stream>>>(
            ray_depth, z_vals, weights, ray_mask, partials, n_rays);
    } else {
        hipMemsetAsync(partials, 0, 3 * NW * sizeof(float), stream);
        const int blocks = (n_rays + 3) / 4;
        sight_near_loss_generic<<<blocks, 256, 0, stream>>>(
            ray_depth, z_vals, weights, ray_mask, partials, n_rays, S);
    }
    sight_finalize<<<1, 64, 0, stream>>>(partials, (float*)d_out);
}

// Round 8
// 139.522 us; speedup vs baseline: 1.3305x; 1.0218x over previous
//
#include <hip/hip_runtime.h>

#define EPSILON 0.05f
#define NW 2048   // persistent waves in fused kernel (512 blocks x 4 waves)

typedef float v4f __attribute__((ext_vector_type(4)));

// Fused persistent kernel (S=1024).
// Phase A: lane j loads mask of ray (wave + j*NW); ONLY masked lanes run the
//   dual binary search (unmasked rays contribute 0 to both losses -- ~50% of
//   rays skipped entirely, halving search + stream traffic).
// Phase B: loop over the wave's rays in pairs; bounds/mask come from
//   v_readlane (registers). steps = fm ? ceil(upper/256) : 0, so unmasked
//   rays issue ZERO weight loads. Direct-write per-wave partials: no atomics,
//   no zero-init.
__global__ __launch_bounds__(256, 4) void sight_fused_1024(
    const float* __restrict__ ray_depth,   // [N]
    const float* __restrict__ z_vals,      // [N, 1024] sorted rows
    const float* __restrict__ weights,     // [N, 1024]
    const int*   __restrict__ ray_mask,    // [N]
    float* __restrict__ partials,          // [3*NW]
    int n_rays)
{
    const int lane = threadIdx.x & 63;
    const int wave = (int)((blockIdx.x * blockDim.x + threadIdx.x) >> 6); // 0..NW-1
    const int rpw  = (n_rays + NW - 1) / NW;   // rays per wave (<=64)

    // ---- Phase A: mask-gated per-lane dual binary search ----
    const int  rj  = wave + lane * NW;
    const bool vld = (lane < rpw) && (rj < n_rays);
    const int  rc  = vld ? rj : 0;
    const int  mk  = vld ? ray_mask[rc] : 0;

    int mypk = 0;
    if (mk != 0) {                      // divergent; inactive lanes issue no loads
        const float d  = ray_depth[rc];
        const float lo = d - EPSILON;
        const float hi = d + EPSILON;
        const float* zr = z_vals + (size_t)rc * 1024;
        int l1 = 0, h1 = 1024, l2 = 0, h2 = 1024;
        #pragma unroll
        for (int it = 0; it < 10; ++it) {
            const int m1 = (l1 + h1) >> 1;
            const int m2 = (l2 + h2) >> 1;
            const float a = zr[m1];
            const float b = zr[m2];
            if (a < lo) l1 = m1 + 1; else h1 = m1;
            if (b < hi) l2 = m2 + 1; else h2 = m2;
        }
        mypk = (int)((unsigned)l1 | ((unsigned)l2 << 16) | 0x80000000u);
    }

    // ---- Phase B: stream weights (masked rays only), ray pairs ----
    float e_lane = 0.0f;   // sum fm * w^2 over [0, lower)
    float n_acc  = 0.0f;   // sum fm * (1 - w_near)^2
    float m_acc  = 0.0f;   // sum fm

    for (int i = 0; i < rpw; i += 2) {
        const int pkA = __builtin_amdgcn_readlane(mypk, i);
        const int pkB = (i + 1 < rpw) ? __builtin_amdgcn_readlane(mypk, i + 1) : 0;

        const int   lowA = pkA & 0xffff,          lowB = pkB & 0xffff;
        const int   upA  = (pkA >> 16) & 0x7fff,  upB  = (pkB >> 16) & 0x7fff;
        const bool  mA   = ((unsigned)pkA >> 31) != 0;
        const bool  mB   = ((unsigned)pkB >> 31) != 0;
        const float fmA  = mA ? 1.0f : 0.0f;
        const float fmB  = mB ? 1.0f : 0.0f;
        const int   stA  = mA ? ((upA + 255) >> 8) : 0;   // chunks (0..4)
        const int   stB  = mB ? ((upB + 255) >> 8) : 0;

        const v4f* wA = (const v4f*)(weights + (size_t)wave * 1024 + (size_t)i * NW * 1024);
        const v4f* wB = (const v4f*)(weights + (size_t)wave * 1024 + (size_t)(i + 1) * NW * 1024);

        v4f a[4], b[4];
        #pragma unroll
        for (int s = 0; s < 4; ++s)
            a[s] = (s < stA) ? wA[lane + 64 * s] : (v4f){0.0f, 0.0f, 0.0f, 0.0f};
        #pragma unroll
        for (int s = 0; s < 4; ++s)
            b[s] = (s < stB) ? wB[lane + 64 * s] : (v4f){0.0f, 0.0f, 0.0f, 0.0f};

        float eA = 0.0f, wnA = 0.0f, eB = 0.0f, wnB = 0.0f;
        #pragma unroll
        for (int s = 0; s < 4; ++s) {
            #pragma unroll
            for (int c = 0; c < 4; ++c) {
                const int   j  = 256 * s + 4 * lane + c;
                const float wa = a[s][c];
                const float wb = b[s][c];
                eA  += (j < lowA) ? wa * wa : 0.0f;
                wnA += (j >= lowA && j < upA) ? wa : 0.0f;
                eB  += (j < lowB) ? wb * wb : 0.0f;
                wnB += (j >= lowB && j < upB) ? wb : 0.0f;
            }
        }
        #pragma unroll
        for (int off = 32; off > 0; off >>= 1) {
            wnA += __shfl_xor(wnA, off, 64);
            wnB += __shfl_xor(wnB, off, 64);
        }
        const float tA = 1.0f - wnA, tB = 1.0f - wnB;
        e_lane += fmA * eA + fmB * eB;
        n_acc  += fmA * tA * tA + fmB * tB * tB;
        m_acc  += fmA + fmB;
    }

    #pragma unroll
    for (int off = 32; off > 0; off >>= 1) e_lane += __shfl_xor(e_lane, off, 64);

    if (lane == 0) {
        partials[wave]          = e_lane;
        partials[NW + wave]     = n_acc;
        partials[2 * NW + wave] = m_acc;
    }
}

// Generic fallback (runtime S): full elementwise pass, atomics into the
// same [3*NW] partials (launcher memsets on this path).
__global__ __launch_bounds__(256) void sight_near_loss_generic(
    const float* __restrict__ ray_depth,
    const float* __restrict__ z_vals,
    const float* __restrict__ weights,
    const int*   __restrict__ ray_mask,
    float* __restrict__ partials,
    int n_rays, int S)
{
    const int wv = threadIdx.x >> 6;
    const int lane = threadIdx.x & 63;
    const int r = blockIdx.x * 4 + wv;
    if (r >= n_rays) return;

    const float d  = ray_depth[r];
    const float lo = d - EPSILON;
    const float hi = d + EPSILON;

    float empty = 0.0f, wnear = 0.0f;
    const float* zr = z_vals  + (size_t)r * S;
    const float* wr = weights + (size_t)r * S;
    for (int k = lane; k < S; k += 64) {
        const float z = zr[k];
        const float w = wr[k];
        empty += (z < lo) ? w * w : 0.0f;
        wnear += (z >= lo && z < hi) ? w : 0.0f;
    }
    #pragma unroll
    for (int off = 32; off > 0; off >>= 1) {
        empty += __shfl_xor(empty, off, 64);
        wnear += __shfl_xor(wnear, off, 64);
    }
    if (lane == 0 && ray_mask[r] != 0) {
        const int slot = r & (NW - 1);
        const float t = 1.0f - wnear;
        atomicAdd(&partials[slot],          empty);
        atomicAdd(&partials[NW + slot],     t * t);
        atomicAdd(&partials[2 * NW + slot], 1.0f);
    }
}

// Reduce [3*NW] partials with one wave (v4f loads).
__global__ void sight_finalize(const float* __restrict__ partials,
                               float* __restrict__ out)
{
    const int lane = threadIdx.x;  // 64 threads
    const v4f* p = (const v4f*)partials;   // each array = NW/4 = 512 v4f
    v4f e4 = {0,0,0,0}, n4 = {0,0,0,0}, m4 = {0,0,0,0};
    #pragma unroll
    for (int k = 0; k < NW / 4 / 64; ++k) {   // 8
        e4 += p[lane + 64 * k];
        n4 += p[512 + lane + 64 * k];
        m4 += p[1024 + lane + 64 * k];
    }
    float e = e4.x + e4.y + e4.z + e4.w;
    float n = n4.x + n4.y + n4.z + n4.w;
    float m = m4.x + m4.y + m4.z + m4.w;
    #pragma unroll
    for (int off = 32; off > 0; off >>= 1) {
        e += __shfl_xor(e, off, 64);
        n += __shfl_xor(n, off, 64);
        m += __shfl_xor(m, off, 64);
    }
    if (lane == 0) {
        out[0] = e / m;   // loss_empty
        out[1] = n / m;   // loss_near
    }
}

extern "C" void kernel_launch(void* const* d_in, const int* in_sizes, int n_in,
                              void* d_out, int out_size, void* d_ws, size_t ws_size,
                              hipStream_t stream) {
    const float* ray_depth = (const float*)d_in[0];
    const float* z_vals    = (const float*)d_in[1];
    const float* weights   = (const float*)d_in[2];
    const int*   ray_mask  = (const int*)d_in[3];

    const int n_rays = in_sizes[0];                // ray_depth is [N,1]
    const int S      = in_sizes[1] / n_rays;       // 1024

    float* partials = (float*)d_ws;                // 3*NW floats = 24 KB

    if (S == 1024 && n_rays <= NW * 64) {
        // fused path writes every slot directly -- no memset needed
        sight_fused_1024<<<NW / 4, 256, 0, stream>>>(
            ray_depth, z_vals, weights, ray_mask, partials, n_rays);
    } else {
        hipMemsetAsync(partials, 0, 3 * NW * sizeof(float), stream);
        const int blocks = (n_rays + 3) / 4;
        sight_near_loss_generic<<<blocks, 256, 0, stream>>>(
            ray_depth, z_vals, weights, ray_mask, partials, n_rays, S);
    }
    sight_finalize<<<1, 64, 0, stream>>>(partials, (float*)d_out);
}